// Round 4
// baseline (216.183 us; speedup 1.0000x reference)
//
#include <hip/hip_runtime.h>
#include <hip/hip_bf16.h>

#define B_  4
#define C_  256
#define C8_ 32
#define N_  16384

typedef unsigned short ushort_t;
typedef __attribute__((ext_vector_type(8))) short short8;
typedef __attribute__((ext_vector_type(4))) float floatx4;

__device__ __forceinline__ short bf16_rne(float f) {
  unsigned u = __float_as_uint(f);
  u += 0x7fffu + ((u >> 16) & 1u);
  return (short)(u >> 16);
}

// K0: cast Wk -> bf16. grid 32 x 256.
__global__ __launch_bounds__(256) void k0_init(const float* __restrict__ Wk,
                                               ushort_t* __restrict__ Wkb) {
  const int i = blockIdx.x * 256 + threadIdx.x;
  Wkb[i] = (ushort_t)bf16_rne(Wk[i]);
}

// Shared swizzled-LDS geometry: 256 c-rows x 64 n bf16 (32KB).
#define XC_IDX(c, n) (((c) << 6) + ((n) ^ (((((c) & 7) ^ (((c) >> 3) & 7))) << 3)))
#define PT_IDX(o, n) (((o) << 6) + ((n) ^ ((((o) & 7)) << 3)))

// K1 (fused transpose-gather + p + kxp partial), v4: NO xT write, kxp bf16.
// Per (b, 64n chunk): stage x fp32->bf16 swizzled LDS; transpose-gather B-frags;
// p-MFMA (Wk A direct); exp+bk -> den wave-partials + PT LDS; phase-B kxp MFMA.
// grid 1024 = B*256, block 256 = 4 waves.
__global__ __launch_bounds__(256) void k1_fused(const float* __restrict__ x,
                                                const ushort_t* __restrict__ Wkb,
                                                const float* __restrict__ bk,
                                                float* __restrict__ denp,
                                                ushort_t* __restrict__ kxp) {
  __shared__ ushort_t XC[256 * 64];  // 32KB bf16 x-tile [c][n], XOR-swizzled
  __shared__ ushort_t PT[32 * 64];   // 4KB bf16 p-tile [o][n], XOR-swizzled
  const int t = threadIdx.x;
  const int lane = t & 63;
  const int w = t >> 6;
  const int b = blockIdx.x >> 8;
  const int chunk = blockIdx.x & 255;
  const int n0 = chunk * 64;
  const int l15 = lane & 15, l4 = lane >> 4;

  // ---- stage x -> LDS (4 passes of 64 c-rows; 4 threads/row) ----
  const int cr = t >> 2, q = t & 3;
#pragma unroll
  for (int pi = 0; pi < 4; ++pi) {
    const int c = pi * 64 + cr;
    const float* xp = x + (size_t)(b * C_ + c) * N_ + n0 + q * 4;
#pragma unroll
    for (int i = 0; i < 4; ++i) {
      float4 v = *(const float4*)(xp + i * 16);
      __hip_bfloat162 h0 = __float22bfloat162_rn(make_float2(v.x, v.y));
      __hip_bfloat162 h1 = __float22bfloat162_rn(make_float2(v.z, v.w));
      const int n = q * 4 + i * 16;
      unsigned* d = (unsigned*)&XC[XC_IDX(c, n)];
      d[0] = *(unsigned*)&h0;
      d[1] = *(unsigned*)&h1;
    }
  }
  __syncthreads();

  // ---- phase A: transpose-gather (x^T B-frags), p-MFMA ----
  const int nl = w * 16 + l15;  // local n of this lane
  short8 bfr[8];
#pragma unroll
  for (int kc = 0; kc < 8; ++kc) {
    const int cb = kc * 32 + l4 * 8;
    short8 v;
#pragma unroll
    for (int j = 0; j < 8; ++j)
      v[j] = (short)XC[XC_IDX(cb + j, nl)];
    bfr[kc] = v;
  }
  const floatx4 z = {0.f, 0.f, 0.f, 0.f};
  floatx4 acc[2];
  acc[0] = z; acc[1] = z;
#pragma unroll
  for (int kc = 0; kc < 8; ++kc) {
    short8 a0 = *(const short8*)&Wkb[l15 * C_ + kc * 32 + l4 * 8];
    short8 a1 = *(const short8*)&Wkb[(16 + l15) * C_ + kc * 32 + l4 * 8];
    acc[0] = __builtin_amdgcn_mfma_f32_16x16x32_bf16(a0, bfr[kc], acc[0], 0, 0, 0);
    acc[1] = __builtin_amdgcn_mfma_f32_16x16x32_bf16(a1, bfr[kc], acc[1], 0, 0, 0);
  }
  // exp, den wave-partials, p -> LDS
  float* dwp = denp + ((size_t)blockIdx.x * 4 + w) * C8_;
#pragma unroll
  for (int mt = 0; mt < 2; ++mt) {
#pragma unroll
    for (int rg = 0; rg < 4; ++rg) {
      const int o = mt * 16 + l4 * 4 + rg;
      float pe = __expf(acc[mt][rg] + bk[o]);
      PT[PT_IDX(o, nl)] = (ushort_t)bf16_rne(pe);
      float s = pe;
      s += __shfl_xor(s, 1); s += __shfl_xor(s, 2);
      s += __shfl_xor(s, 4); s += __shfl_xor(s, 8);
      if (l15 == 0) dwp[o] = s;
    }
  }
  __syncthreads();

  // ---- phase B: kxp partial. wave w owns c-quarter [w*64, w*64+64). ----
  floatx4 ka[2][4];
#pragma unroll
  for (int ot = 0; ot < 2; ++ot)
#pragma unroll
    for (int ct = 0; ct < 4; ++ct) ka[ot][ct] = z;
#pragma unroll
  for (int kn = 0; kn < 2; ++kn) {
    const int nb = kn * 32 + l4 * 8;
    short8 pa0 = *(const short8*)&PT[PT_IDX(l15, nb)];
    short8 pa1 = *(const short8*)&PT[PT_IDX(16 + l15, nb)];
#pragma unroll
    for (int ct = 0; ct < 4; ++ct) {
      const int c = w * 64 + ct * 16 + l15;
      short8 xb = *(const short8*)&XC[XC_IDX(c, nb)];
      ka[0][ct] = __builtin_amdgcn_mfma_f32_16x16x32_bf16(pa0, xb, ka[0][ct], 0, 0, 0);
      ka[1][ct] = __builtin_amdgcn_mfma_f32_16x16x32_bf16(pa1, xb, ka[1][ct], 0, 0, 0);
    }
  }
  // kxp[b][chunk][o][c] bf16
  ushort_t* dst = kxp + (size_t)(b * 256 + chunk) * (C8_ * C_);
#pragma unroll
  for (int ot = 0; ot < 2; ++ot)
#pragma unroll
    for (int ct = 0; ct < 4; ++ct)
#pragma unroll
      for (int rg = 0; rg < 4; ++rg) {
        const int o = ot * 16 + l4 * 4 + rg;
        const int c = w * 64 + ct * 16 + l15;
        dst[o * C_ + c] = (ushort_t)bf16_rne(ka[ot][ct][rg]);
      }
}

// K3b: den[b][o] = sum of 1024 wave-partials; kx = (sum_ch kxp bf16)/den.
// grid 512 = b*128 + o*4 + cq; block 256 (4-way chunk split x 64 c).
__global__ __launch_bounds__(256) void k3b_reduce(const ushort_t* __restrict__ kxp,
                                                  const float* __restrict__ denp,
                                                  float* __restrict__ kx) {
  __shared__ float red[256];
  __shared__ float csum[256];
  const int t = threadIdx.x;
  const int b = blockIdx.x >> 7;
  const int o = (blockIdx.x >> 2) & 31;
  const int cq = blockIdx.x & 3;
  float ds = 0.f;
#pragma unroll
  for (int k = 0; k < 4; ++k)
    ds += denp[(size_t)(b * 1024 + k * 256 + t) * C8_ + o];
  red[t] = ds;
  __syncthreads();
  for (int st = 128; st > 0; st >>= 1) {
    if (t < st) red[t] += red[t + st];
    __syncthreads();
  }
  const float inv = 1.0f / red[0];
  const int c = cq * 64 + (t & 63);
  const int part = t >> 6;
  float s = 0.f;
#pragma unroll 8
  for (int j = 0; j < 64; ++j) {
    unsigned u = kxp[((size_t)(b * 256 + part * 64 + j) * C8_ + o) * C_ + c];
    s += __uint_as_float(u << 16);
  }
  csum[t] = s;
  __syncthreads();
  if (part == 0) {
    float tot = s + csum[64 + t] + csum[128 + t] + csum[192 + t];
    kx[(size_t)(b * C8_ + o) * C_ + c] = tot * inv;
  }
}

// K4a: kv[b][o][c] = Wv[c][:].kx[b][o][:] + bv[c]. grid 128, thread = c.
__global__ __launch_bounds__(256) void k4a_kv(const float* __restrict__ Wv,
                                              const float* __restrict__ bv,
                                              const float* __restrict__ kx,
                                              float* __restrict__ kv) {
  __shared__ float kxl[C_];
  const int t = threadIdx.x;
  const int bo = blockIdx.x;
  kxl[t] = kx[(size_t)bo * C_ + t];
  __syncthreads();
  const float4* wr = (const float4*)&Wv[(size_t)t * C_];
  float s = 0.f;
#pragma unroll 8
  for (int c4 = 0; c4 < 64; ++c4) {
    float4 wv = wr[c4];
    float4 k4 = *(const float4*)&kxl[c4 * 4];
    s += wv.x * k4.x + wv.y * k4.y + wv.z * k4.z + wv.w * k4.w;
  }
  kv[(size_t)bo * C_ + t] = s + bv[t];
}

// K4b: Mt[b][c][c''] bf16 (rows = out-channel c, K5's B operand); r[b][c]. grid 64.
__global__ __launch_bounds__(256) void k4b_M(const float* __restrict__ Wq,
                                             const float* __restrict__ bq,
                                             const float* __restrict__ kv,
                                             ushort_t* __restrict__ Mt,
                                             float* __restrict__ r) {
  __shared__ float kvl[C8_ * C_];
  __shared__ float wqT[16 * C8_];
  const int t = threadIdx.x;
  const int b = blockIdx.x >> 4;
  const int c0 = (blockIdx.x & 15) * 16;
  for (int s = 0; s < 32; ++s)
    kvl[s * 256 + t] = kv[(size_t)b * C8_ * C_ + s * 256 + t];
#pragma unroll
  for (int s = 0; s < 2; ++s) {
    int f = s * 256 + t;
    int o = f >> 4, i = f & 15;
    wqT[i * C8_ + o] = Wq[o * C_ + c0 + i];
  }
  __syncthreads();
  float kvreg[C8_];
#pragma unroll
  for (int o = 0; o < C8_; ++o) kvreg[o] = kvl[o * C_ + t];
  ushort_t mrow[16];
#pragma unroll
  for (int i = 0; i < 16; ++i) {
    const float4* w4 = (const float4*)&wqT[i * C8_];
    float s = 0.f;
#pragma unroll
    for (int o8 = 0; o8 < 8; ++o8) {
      float4 wv = w4[o8];
      s += wv.x * kvreg[o8 * 4] + wv.y * kvreg[o8 * 4 + 1] +
           wv.z * kvreg[o8 * 4 + 2] + wv.w * kvreg[o8 * 4 + 3];
    }
    mrow[i] = (ushort_t)bf16_rne(s);
  }
  ushort_t* mdst = Mt + (size_t)(b * C_ + t) * C_ + c0;
  *(uint4*)(mdst) = *(uint4*)&mrow[0];
  *(uint4*)(mdst + 8) = *(uint4*)&mrow[8];
  if (c0 == 0) {
    float rr = 0.f;
#pragma unroll
    for (int o = 0; o < C8_; ++o) rr += bq[o] * kvreg[o];
    r[b * C_ + t] = rr;
  }
}

// K5 v4: out[f=(b*N+n)*C+c] = g*(attn[n][c] + r[c]) + x_flat[f]. NO xT:
// x-tile staged fp32->bf16 swizzled LDS; A = x^T frags via transpose-gather
// (k1's proven pattern); B = direct short8 rows of Mt (L2-resident).
// grid 1024 = B*256 nt (64n), block 4 waves; wave = 64n x 64c (4m x 4j x 8k).
__global__ __launch_bounds__(256, 4) void k5_mfma(const float* __restrict__ x,
                                                  const ushort_t* __restrict__ Mt,
                                                  const float* __restrict__ r,
                                                  const float* __restrict__ gamma_p,
                                                  float* __restrict__ out) {
  __shared__ ushort_t XC[256 * 64];  // 32KB bf16 x-tile [c''][n], XOR-swizzled
  const int t = threadIdx.x;
  const int lane = t & 63;
  const int w = t >> 6;
  const int b = blockIdx.x >> 8;
  const int nt = blockIdx.x & 255;
  const int n0 = nt * 64;
  const int l15 = lane & 15, l4 = lane >> 4;

  // ---- stage x -> LDS (identical pattern to k1) ----
  const int cr = t >> 2, q = t & 3;
#pragma unroll
  for (int pi = 0; pi < 4; ++pi) {
    const int c = pi * 64 + cr;
    const float* xp = x + (size_t)(b * C_ + c) * N_ + n0 + q * 4;
#pragma unroll
    for (int i = 0; i < 4; ++i) {
      float4 v = *(const float4*)(xp + i * 16);
      __hip_bfloat162 h0 = __float22bfloat162_rn(make_float2(v.x, v.y));
      __hip_bfloat162 h1 = __float22bfloat162_rn(make_float2(v.z, v.w));
      const int n = q * 4 + i * 16;
      unsigned* d = (unsigned*)&XC[XC_IDX(c, n)];
      d[0] = *(unsigned*)&h0;
      d[1] = *(unsigned*)&h1;
    }
  }
  __syncthreads();

  const floatx4 z = {0.f, 0.f, 0.f, 0.f};
  floatx4 acc[4][4];
#pragma unroll
  for (int mt = 0; mt < 4; ++mt)
#pragma unroll
    for (int jt = 0; jt < 4; ++jt) acc[mt][jt] = z;

  const ushort_t* MtB = Mt + (size_t)(b * C_ + w * 64) * C_;  // wave's c-quarter
#pragma unroll
  for (int kc = 0; kc < 8; ++kc) {
    const int cb = kc * 32 + l4 * 8;
    short8 bm[4];
#pragma unroll
    for (int jt = 0; jt < 4; ++jt)
      bm[jt] = *(const short8*)&MtB[(size_t)(jt * 16 + l15) * C_ + cb];
    short8 am[4];
#pragma unroll
    for (int mt = 0; mt < 4; ++mt) {
      const int nl = mt * 16 + l15;
      short8 v;
#pragma unroll
      for (int e = 0; e < 8; ++e)
        v[e] = (short)XC[XC_IDX(cb + e, nl)];
      am[mt] = v;
    }
#pragma unroll
    for (int mt = 0; mt < 4; ++mt)
#pragma unroll
      for (int jt = 0; jt < 4; ++jt)
        acc[mt][jt] = __builtin_amdgcn_mfma_f32_16x16x32_bf16(am[mt], bm[jt], acc[mt][jt], 0, 0, 0);
  }

  const float g = gamma_p[0];
  float rr4[4];
#pragma unroll
  for (int jt = 0; jt < 4; ++jt) rr4[jt] = r[b * C_ + w * 64 + jt * 16 + l15];
#pragma unroll
  for (int mt = 0; mt < 4; ++mt)
#pragma unroll
    for (int rg = 0; rg < 4; ++rg) {
      const int n = n0 + mt * 16 + l4 * 4 + rg;
#pragma unroll
      for (int jt = 0; jt < 4; ++jt) {
        const int c = w * 64 + jt * 16 + l15;
        const size_t f = ((size_t)b * N_ + n) * C_ + c;
        out[f] = g * (acc[mt][jt][rg] + rr4[jt]) + x[f];
      }
    }
}

extern "C" void kernel_launch(void* const* d_in, const int* in_sizes, int n_in,
                              void* d_out, int out_size, void* d_ws, size_t ws_size,
                              hipStream_t stream) {
  const float* x  = (const float*)d_in[0];
  const float* Wq = (const float*)d_in[1];
  const float* bq = (const float*)d_in[2];
  const float* Wk = (const float*)d_in[3];
  const float* bk = (const float*)d_in[4];
  const float* Wv = (const float*)d_in[5];
  const float* bv = (const float*)d_in[6];
  const float* gm = (const float*)d_in[7];
  float* out = (float*)d_out;

  float* ws = (float*)d_ws;
  ushort_t* Wkb  = (ushort_t*)ws;                        // 8192 us = 4096 fl
  float*    denp = ws + 4096;                            // 1024*4*32 = 131072 fl
  ushort_t* kxp  = (ushort_t*)(ws + 4096 + 131072);      // 8388608 us = 4194304 fl
  float*    kx   = ws + 4096 + 131072 + 4194304;         // 32768 fl
  float*    kv   = kx + 32768;                           // 32768 fl
  ushort_t* Mt   = (ushort_t*)(kv + 32768);              // 262144 us = 131072 fl... (65536 fl used)
  float*    r    = (float*)(kv + 32768 + 131072);        // 1024 fl

  k0_init   <<<32,   256, 0, stream>>>(Wk, Wkb);
  k1_fused  <<<1024, 256, 0, stream>>>(x, Wkb, bk, denp, kxp);
  k3b_reduce<<<512,  256, 0, stream>>>(kxp, denp, kx);
  k4a_kv    <<<128,  256, 0, stream>>>(Wv, bv, kx, kv);
  k4b_M     <<<64,   256, 0, stream>>>(Wq, bq, kv, Mt, r);
  k5_mfma   <<<1024, 256, 0, stream>>>(x, Mt, r, gm, out);
}

// Round 5
// 182.406 us; speedup vs baseline: 1.1852x; 1.1852x over previous
//
#include <hip/hip_runtime.h>
#include <hip/hip_bf16.h>

#define B_  4
#define C_  256
#define C8_ 32
#define N_  16384

typedef unsigned short ushort_t;
typedef __attribute__((ext_vector_type(8))) short short8;
typedef __attribute__((ext_vector_type(4))) float floatx4;

__device__ __forceinline__ short bf16_rne(float f) {
  unsigned u = __float_as_uint(f);
  u += 0x7fffu + ((u >> 16) & 1u);
  return (short)(u >> 16);
}

// K0: cast Wk -> bf16. grid 32 x 256.
__global__ __launch_bounds__(256) void k0_init(const float* __restrict__ Wk,
                                               ushort_t* __restrict__ Wkb) {
  const int i = blockIdx.x * 256 + threadIdx.x;
  Wkb[i] = (ushort_t)bf16_rne(Wk[i]);
}

// Swizzled-LDS geometry: 256 c-rows x 64 n bf16 (32KB).
#define XC_IDX(c, n) (((c) << 6) + ((n) ^ (((((c) & 7) ^ (((c) >> 3) & 7))) << 3)))
#define PT_IDX(o, n) (((o) << 6) + ((n) ^ ((((o) & 7)) << 3)))

// K1 (fused transpose + p + kxp partial) — round-1 proven structure,
// only delta: kxp stored bf16 (-16.8 MB write).
// grid 1024 = B*256 (64n chunks), block 256 = 4 waves.
__global__ __launch_bounds__(256) void k1_fused(const float* __restrict__ x,
                                                const ushort_t* __restrict__ Wkb,
                                                const float* __restrict__ bk,
                                                ushort_t* __restrict__ xT,
                                                float* __restrict__ denp,
                                                ushort_t* __restrict__ kxp) {
  __shared__ ushort_t XC[256 * 64];  // 32KB bf16 x-tile [c][n], XOR-swizzled
  __shared__ ushort_t PT[32 * 64];   // 4KB bf16 p-tile [o][n], XOR-swizzled
  const int t = threadIdx.x;
  const int lane = t & 63;
  const int w = t >> 6;
  const int b = blockIdx.x >> 8;
  const int chunk = blockIdx.x & 255;
  const int n0 = chunk * 64;
  const int l15 = lane & 15, l4 = lane >> 4;

  // ---- stage x -> LDS (4 passes of 64 c-rows; 4 threads/row) ----
  const int cr = t >> 2, q = t & 3;
#pragma unroll
  for (int pi = 0; pi < 4; ++pi) {
    const int c = pi * 64 + cr;
    const float* xp = x + (size_t)(b * C_ + c) * N_ + n0 + q * 4;
#pragma unroll
    for (int i = 0; i < 4; ++i) {
      float4 v = *(const float4*)(xp + i * 16);
      __hip_bfloat162 h0 = __float22bfloat162_rn(make_float2(v.x, v.y));
      __hip_bfloat162 h1 = __float22bfloat162_rn(make_float2(v.z, v.w));
      const int n = q * 4 + i * 16;
      unsigned* d = (unsigned*)&XC[XC_IDX(c, n)];
      d[0] = *(unsigned*)&h0;
      d[1] = *(unsigned*)&h1;
    }
  }
  __syncthreads();

  // ---- phase A: transpose-gather (x^T B-frags), xT write, p-MFMA ----
  const int nl = w * 16 + l15;  // local n of this lane
  short8 bfr[8];
#pragma unroll
  for (int kc = 0; kc < 8; ++kc) {
    const int cb = kc * 32 + l4 * 8;
    short8 v;
#pragma unroll
    for (int j = 0; j < 8; ++j)
      v[j] = (short)XC[XC_IDX(cb + j, nl)];
    bfr[kc] = v;
    *(short8*)&xT[(size_t)(b * N_ + n0 + nl) * C_ + cb] = v;
  }
  const floatx4 z = {0.f, 0.f, 0.f, 0.f};
  floatx4 acc[2];
  acc[0] = z; acc[1] = z;
#pragma unroll
  for (int kc = 0; kc < 8; ++kc) {
    short8 a0 = *(const short8*)&Wkb[l15 * C_ + kc * 32 + l4 * 8];
    short8 a1 = *(const short8*)&Wkb[(16 + l15) * C_ + kc * 32 + l4 * 8];
    acc[0] = __builtin_amdgcn_mfma_f32_16x16x32_bf16(a0, bfr[kc], acc[0], 0, 0, 0);
    acc[1] = __builtin_amdgcn_mfma_f32_16x16x32_bf16(a1, bfr[kc], acc[1], 0, 0, 0);
  }
  // exp, den wave-partials, p -> LDS
  float* dwp = denp + ((size_t)blockIdx.x * 4 + w) * C8_;
#pragma unroll
  for (int mt = 0; mt < 2; ++mt) {
#pragma unroll
    for (int rg = 0; rg < 4; ++rg) {
      const int o = mt * 16 + l4 * 4 + rg;
      float pe = __expf(acc[mt][rg] + bk[o]);
      PT[PT_IDX(o, nl)] = (ushort_t)bf16_rne(pe);
      float s = pe;
      s += __shfl_xor(s, 1); s += __shfl_xor(s, 2);
      s += __shfl_xor(s, 4); s += __shfl_xor(s, 8);
      if (l15 == 0) dwp[o] = s;
    }
  }
  __syncthreads();

  // ---- phase B: kxp partial. wave w owns c-quarter [w*64, w*64+64). ----
  floatx4 ka[2][4];
#pragma unroll
  for (int ot = 0; ot < 2; ++ot)
#pragma unroll
    for (int ct = 0; ct < 4; ++ct) ka[ot][ct] = z;
#pragma unroll
  for (int kn = 0; kn < 2; ++kn) {
    const int nb = kn * 32 + l4 * 8;
    short8 pa0 = *(const short8*)&PT[PT_IDX(l15, nb)];
    short8 pa1 = *(const short8*)&PT[PT_IDX(16 + l15, nb)];
#pragma unroll
    for (int ct = 0; ct < 4; ++ct) {
      const int c = w * 64 + ct * 16 + l15;
      short8 xb = *(const short8*)&XC[XC_IDX(c, nb)];
      ka[0][ct] = __builtin_amdgcn_mfma_f32_16x16x32_bf16(pa0, xb, ka[0][ct], 0, 0, 0);
      ka[1][ct] = __builtin_amdgcn_mfma_f32_16x16x32_bf16(pa1, xb, ka[1][ct], 0, 0, 0);
    }
  }
  // kxp[b][chunk][o][c] bf16
  ushort_t* dst = kxp + (size_t)(b * 256 + chunk) * (C8_ * C_);
#pragma unroll
  for (int ot = 0; ot < 2; ++ot)
#pragma unroll
    for (int ct = 0; ct < 4; ++ct)
#pragma unroll
      for (int rg = 0; rg < 4; ++rg) {
        const int o = ot * 16 + l4 * 4 + rg;
        const int c = w * 64 + ct * 16 + l15;
        dst[o * C_ + c] = (ushort_t)bf16_rne(ka[ot][ct][rg]);
      }
}

// K3b: den[b][o] = sum of 1024 wave-partials; kx = (sum_ch kxp bf16)/den.
// grid 512 = b*128 + o*4 + cq; block 256 (4-way chunk split x 64 c).
__global__ __launch_bounds__(256) void k3b_reduce(const ushort_t* __restrict__ kxp,
                                                  const float* __restrict__ denp,
                                                  float* __restrict__ kx) {
  __shared__ float red[256];
  __shared__ float csum[256];
  const int t = threadIdx.x;
  const int b = blockIdx.x >> 7;
  const int o = (blockIdx.x >> 2) & 31;
  const int cq = blockIdx.x & 3;
  float ds = 0.f;
#pragma unroll
  for (int k = 0; k < 4; ++k)
    ds += denp[(size_t)(b * 1024 + k * 256 + t) * C8_ + o];
  red[t] = ds;
  __syncthreads();
  for (int st = 128; st > 0; st >>= 1) {
    if (t < st) red[t] += red[t + st];
    __syncthreads();
  }
  const float inv = 1.0f / red[0];
  const int c = cq * 64 + (t & 63);
  const int part = t >> 6;
  float s = 0.f;
#pragma unroll 8
  for (int j = 0; j < 64; ++j) {
    unsigned u = kxp[((size_t)(b * 256 + part * 64 + j) * C8_ + o) * C_ + c];
    s += __uint_as_float(u << 16);
  }
  csum[t] = s;
  __syncthreads();
  if (part == 0) {
    float tot = s + csum[64 + t] + csum[128 + t] + csum[192 + t];
    kx[(size_t)(b * C8_ + o) * C_ + c] = tot * inv;
  }
}

// K4a: kv[b][o][c] = Wv[c][:].kx[b][o][:] + bv[c]. grid 128, thread = c.
__global__ __launch_bounds__(256) void k4a_kv(const float* __restrict__ Wv,
                                              const float* __restrict__ bv,
                                              const float* __restrict__ kx,
                                              float* __restrict__ kv) {
  __shared__ float kxl[C_];
  const int t = threadIdx.x;
  const int bo = blockIdx.x;
  kxl[t] = kx[(size_t)bo * C_ + t];
  __syncthreads();
  const float4* wr = (const float4*)&Wv[(size_t)t * C_];
  float s = 0.f;
#pragma unroll 8
  for (int c4 = 0; c4 < 64; ++c4) {
    float4 wv = wr[c4];
    float4 k4 = *(const float4*)&kxl[c4 * 4];
    s += wv.x * k4.x + wv.y * k4.y + wv.z * k4.z + wv.w * k4.w;
  }
  kv[(size_t)bo * C_ + t] = s + bv[t];
}

// K4b: Mt[b][c][c''] bf16 (rows = out-channel c); r[b][c]. grid 64.
__global__ __launch_bounds__(256) void k4b_M(const float* __restrict__ Wq,
                                             const float* __restrict__ bq,
                                             const float* __restrict__ kv,
                                             ushort_t* __restrict__ Mt,
                                             float* __restrict__ r) {
  __shared__ float kvl[C8_ * C_];
  __shared__ float wqT[16 * C8_];
  const int t = threadIdx.x;
  const int b = blockIdx.x >> 4;
  const int c0 = (blockIdx.x & 15) * 16;
  for (int s = 0; s < 32; ++s)
    kvl[s * 256 + t] = kv[(size_t)b * C8_ * C_ + s * 256 + t];
#pragma unroll
  for (int s = 0; s < 2; ++s) {
    int f = s * 256 + t;
    int o = f >> 4, i = f & 15;
    wqT[i * C8_ + o] = Wq[o * C_ + c0 + i];
  }
  __syncthreads();
  float kvreg[C8_];
#pragma unroll
  for (int o = 0; o < C8_; ++o) kvreg[o] = kvl[o * C_ + t];
  ushort_t mrow[16];
#pragma unroll
  for (int i = 0; i < 16; ++i) {
    const float4* w4 = (const float4*)&wqT[i * C8_];
    float s = 0.f;
#pragma unroll
    for (int o8 = 0; o8 < 8; ++o8) {
      float4 wv = w4[o8];
      s += wv.x * kvreg[o8 * 4] + wv.y * kvreg[o8 * 4 + 1] +
           wv.z * kvreg[o8 * 4 + 2] + wv.w * kvreg[o8 * 4 + 3];
    }
    mrow[i] = (ushort_t)bf16_rne(s);
  }
  ushort_t* mdst = Mt + (size_t)(b * C_ + t) * C_ + c0;
  *(uint4*)(mdst) = *(uint4*)&mrow[0];
  *(uint4*)(mdst + 8) = *(uint4*)&mrow[8];
  if (c0 == 0) {
    float rr = 0.f;
#pragma unroll
    for (int o = 0; o < C8_; ++o) rr += bq[o] * kvreg[o];
    r[b * C_ + t] = rr;
  }
}

// K5 v5: out.flat[f=n*C+c] = g*(attn[n][c] + r[c]) + x.flat[f].
// Round-1 structure (xT frags + XOR-swizzled MtL staging, 1 barrier) with
// OPERANDS SWAPPED: A = Mt rows (M=c_out), B = xT rows (N=n). D[c][n] gives
// each lane 4 CONSECUTIVE c (rg) -> pure float4 residual loads / r loads /
// out stores (full 64B sectors per instruction, 4x fewer epilogue instrs).
// grid 2048 (XCD-swizzled), block 4 waves = 64n x 128c (ch half).
__global__ __launch_bounds__(256) void k5_mfma(const float* __restrict__ x,
                                               const ushort_t* __restrict__ xT,
                                               const ushort_t* __restrict__ Mt,
                                               const float* __restrict__ r,
                                               const float* __restrict__ gamma_p,
                                               float* __restrict__ out) {
  __shared__ uint4 MtL[4096];  // 128 c-rows x 32 chunks of 16B, XOR-swizzled
  const int wid = (blockIdx.x & 7) * 256 + (blockIdx.x >> 3);  // bijective, 2048%8==0
  const int t = threadIdx.x;
  const int lane = t & 63;
  const int w = t >> 6;
  const int b = wid >> 9;
  const int nt = (wid >> 1) & 255;
  const int ch = wid & 1;
  const int n0 = nt * 64 + w * 16;
  const int c0 = ch * 128;
  const int l15 = lane & 15, l4 = lane >> 4;

  // B-operand frags: xT rows n (N-dim = n = n0 + l15), k along c'' (contiguous)
  short8 a[8];
#pragma unroll
  for (int kc = 0; kc < 8; ++kc)
    a[kc] = *(const short8*)&xT[(size_t)(b * N_ + n0 + l15) * C_ + kc * 32 + l4 * 8];

  // stage Mt c-half into swizzled LDS (identical to round-1)
  const char* Mth = (const char*)(Mt + (size_t)(b * C_ + c0) * C_);
#pragma unroll
  for (int s = 0; s < 16; ++s) {
    const int f = (w * 16 + s) * 1024 + lane * 16;
    const int i = f >> 9, j = (f & 511) >> 4;
    MtL[i * 32 + (j ^ (i & 31))] = *(const uint4*)(Mth + f);
  }
  __syncthreads();

  const floatx4 z = {0.f, 0.f, 0.f, 0.f};
  floatx4 acc[8];
#pragma unroll
  for (int ct = 0; ct < 8; ++ct) acc[ct] = z;
#pragma unroll
  for (int kc = 0; kc < 8; ++kc) {
    const int jj = kc * 4 + l4;
#pragma unroll
    for (int ct = 0; ct < 8; ++ct) {
      const int i = ct * 16 + l15;  // A row = c_out (M-dim)
      short8 am = *(const short8*)&MtL[i * 32 + (jj ^ (i & 31))];
      acc[ct] = __builtin_amdgcn_mfma_f32_16x16x32_bf16(am, a[kc], acc[ct], 0, 0, 0);
    }
  }
  // epilogue: lane holds n = n0+l15 fixed, c = c0+ct*16+l4*4+{0..3} -> float4
  const float g = gamma_p[0];
  const int n = n0 + l15;
#pragma unroll
  for (int ct = 0; ct < 8; ++ct) {
    const int c = c0 + ct * 16 + l4 * 4;
    const size_t f = ((size_t)b * N_ + n) * C_ + c;
    float4 rr = *(const float4*)(r + b * C_ + c);
    float4 xr = *(const float4*)(x + f);
    float4 gv;
    gv.x = g * (acc[ct][0] + rr.x) + xr.x;
    gv.y = g * (acc[ct][1] + rr.y) + xr.y;
    gv.z = g * (acc[ct][2] + rr.z) + xr.z;
    gv.w = g * (acc[ct][3] + rr.w) + xr.w;
    *(float4*)(out + f) = gv;
  }
}

extern "C" void kernel_launch(void* const* d_in, const int* in_sizes, int n_in,
                              void* d_out, int out_size, void* d_ws, size_t ws_size,
                              hipStream_t stream) {
  const float* x  = (const float*)d_in[0];
  const float* Wq = (const float*)d_in[1];
  const float* bq = (const float*)d_in[2];
  const float* Wk = (const float*)d_in[3];
  const float* bk = (const float*)d_in[4];
  const float* Wv = (const float*)d_in[5];
  const float* bv = (const float*)d_in[6];
  const float* gm = (const float*)d_in[7];
  float* out = (float*)d_out;

  float* ws = (float*)d_ws;
  ushort_t* Wkb  = (ushort_t*)ws;                        // 4096 fl
  ushort_t* xT   = (ushort_t*)(ws + 4096);               // 8388608 fl
  float*    denp = ws + 4096 + 8388608;                  // 1024*4*32 = 131072 fl
  ushort_t* kxp  = (ushort_t*)(ws + 4096 + 8388608 + 131072);  // bf16: 4194304 fl
  float*    kx   = ws + 4096 + 8388608 + 131072 + 4194304;     // 32768 fl
  float*    kv   = kx + 32768;                           // 32768 fl
  ushort_t* Mt   = (ushort_t*)(kv + 32768);              // 131072 fl
  float*    r    = (float*)(kv + 32768 + 131072);        // 1024 fl

  k0_init   <<<32,   256, 0, stream>>>(Wk, Wkb);
  k1_fused  <<<1024, 256, 0, stream>>>(x, Wkb, bk, xT, denp, kxp);
  k3b_reduce<<<512,  256, 0, stream>>>(kxp, denp, kx);
  k4a_kv    <<<128,  256, 0, stream>>>(Wv, bv, kx, kv);
  k4b_M     <<<64,   256, 0, stream>>>(Wq, bq, kv, Mt, r);
  k5_mfma   <<<2048, 256, 0, stream>>>(x, xT, Mt, r, gm, out);
}